// Round 6
// baseline (303.093 us; speedup 1.0000x reference)
//
#include <hip/hip_runtime.h>
#include <climits>

#define N_ 16384
#define H_ 256
#define W_ 704
#define HW_ (H_*W_)
#define NC_ (N_*16)
#define EPS_ 1e-3f
#define HDR_ 512

typedef unsigned long long ull;

// ---- workspace layout (float units) ----
// arrays at HDR_: pts_lin(0) pos_lin(1) gath(2) t_lin(3) off(4,5) attn(6) neigh(7) f_lin(8) val(9..)
#define VAL_    (HDR_ + 9*NC_)
#define KNNI_   (VAL_ + HW_*16)          // counts: 180224 ints, then slots: 180224*8 u32
#define PARTK_  (KNNI_ + 1622016)        // 256x32 floats
#define PARTFC_ (PARTK_ + 8192)
#define PARTT_  (PARTK_ + 16384)
#define PARTF2_ (PARTK_ + 24576)
#define SPI_    (PARTK_ + 32768)         // int offset: 64 blocks x 8 ints grid-stat partials

__device__ __forceinline__ float wsum64(float v){
#pragma unroll
  for (int o = 32; o > 0; o >>= 1) v += __shfl_down(v, o);
  return v;
}

#define LOAD16(dst, src) { const float4* _s=(const float4*)(src); float4 _a=_s[0],_b=_s[1],_c=_s[2],_d=_s[3]; \
  dst[0]=_a.x;dst[1]=_a.y;dst[2]=_a.z;dst[3]=_a.w; dst[4]=_b.x;dst[5]=_b.y;dst[6]=_b.z;dst[7]=_b.w; \
  dst[8]=_c.x;dst[9]=_c.y;dst[10]=_c.z;dst[11]=_c.w; dst[12]=_d.x;dst[13]=_d.y;dst[14]=_d.z;dst[15]=_d.w; }

#define STORE16(dst, src) { float4* _d=(float4*)(dst); \
  _d[0]=make_float4(src[0],src[1],src[2],src[3]); _d[1]=make_float4(src[4],src[5],src[6],src[7]); \
  _d[2]=make_float4(src[8],src[9],src[10],src[11]); _d[3]=make_float4(src[12],src[13],src[14],src[15]); }

__device__ __forceinline__ void knn_insert(ull* arr, ull key){
  if (key < arr[8]){
    int q = 8;
    while (q > 0 && arr[q-1] > key){ arr[q] = arr[q-1]; --q; }
    arr[q] = key;
  }
}

// enumerate candidates from padded cell table; lane s handles rows y0+s, +4.
// Latency fix (R6): preload each row-segment's counts with INDEPENDENT register
// loads (contiguous, 1-2 cache lines), then fetch slot lines as uint4 —
// replaces the ~17-deep serial load chain per row with depth ~1.
__device__ __forceinline__ void scan_box_padded(const int* __restrict__ counts,
                                                const unsigned* __restrict__ slots,
                                                int y, int x, int s,
                                                int y0, int y1, int x0, int x1, ull* arr){
  for (int yy=y0+s; yy<=y1; yy+=4){
    const int rowb = yy*W_;
    const int dy = y-yy, dy2 = dy*dy;
    for (int xb = x0; xb <= x1; xb += 17){
      const int ncell = min(17, x1 - xb + 1);
      int cc[17];
#pragma unroll
      for (int j=0;j<17;++j) cc[j] = (j < ncell) ? counts[rowb + xb + j] : 0;
#pragma unroll
      for (int j=0;j<17;++j){
        int c = cc[j];
        if (c > 0){
          c = min(c, 8);
          const uint4* sl4 = (const uint4*)(slots + (ull)(rowb + xb + j)*8);
          const int dx = x - (xb + j);
          const ull base = ((ull)(unsigned)(dy2 + dx*dx)) << 14;
          uint4 a4 = sl4[0];
          knn_insert(arr, base | (ull)(a4.x & 16383u));
          if (c > 1) knn_insert(arr, base | (ull)(a4.y & 16383u));
          if (c > 2) knn_insert(arr, base | (ull)(a4.z & 16383u));
          if (c > 3) knn_insert(arr, base | (ull)(a4.w & 16383u));
          if (c > 4){
            uint4 b4 = sl4[1];
            knn_insert(arr, base | (ull)(b4.x & 16383u));
            if (c > 5) knn_insert(arr, base | (ull)(b4.y & 16383u));
            if (c > 6) knn_insert(arr, base | (ull)(b4.z & 16383u));
            if (c > 7) knn_insert(arr, base | (ull)(b4.w & 16383u));
          }
        }
      }
    }
  }
}

// reduce 256x32 partials -> BN affine coefs into LDS (whole block participates)
__device__ __forceinline__ void red_body(const float* __restrict__ g, const float* __restrict__ bta,
                                         const float* __restrict__ part, float* __restrict__ coef,
                                         float* __restrict__ red){
  int t = threadIdx.x, slot = t & 31, chunk = t >> 5;
  float acc = 0.f;
  for (int bb=chunk*32; bb<chunk*32+32; ++bb) acc += part[bb*32 + slot];
  red[t] = acc;
  __syncthreads();
  if (chunk == 0){
    float v = red[slot];
#pragma unroll
    for (int k2=1;k2<8;++k2) v += red[k2*32+slot];
    red[slot] = v;
  }
  __syncthreads();
  if (t < 16){
    float mu  = red[t]    * (1.f/N_);
    float var = red[16+t] * (1.f/N_) - mu*mu;
    float a = g[t] / sqrtf(var + EPS_);
    coef[t]    = a;
    coef[16+t] = bta[t] - mu*a;
  }
  __syncthreads();
}

// ============ K0: zero cell counts (0..175) || grid-stat partials (176..239) ============
__global__ __launch_bounds__(256) void k0(const int* __restrict__ grid, float* __restrict__ ws){
  const int t = threadIdx.x, b = blockIdx.x;
  if (b < 176){
    int4* c4 = (int4*)(ws + KNNI_);
    c4[b*256 + t] = make_int4(0,0,0,0);
  } else {
    const int sb = b - 176;
    int2 p = ((const int2*)grid)[sb*256 + t];
    int sy=p.x, sx=p.y, mny=p.x, mxy=p.x, mnx=p.y, mxx=p.y;
#pragma unroll
    for (int o=32;o>0;o>>=1){
      sy += __shfl_down(sy,o); sx += __shfl_down(sx,o);
      mny = min(mny,__shfl_down(mny,o)); mxy = max(mxy,__shfl_down(mxy,o));
      mnx = min(mnx,__shfl_down(mnx,o)); mxx = max(mxx,__shfl_down(mxx,o));
    }
    __shared__ int sh[24];
    int w = t >> 6;
    if ((t & 63) == 0){
      sh[w]=sy; sh[4+w]=sx; sh[8+w]=mny; sh[12+w]=mxy; sh[16+w]=mnx; sh[20+w]=mxx;
    }
    __syncthreads();
    if (t == 0){
      int* sp = (int*)ws + SPI_ + sb*8;
      sp[0]=sh[0]+sh[1]+sh[2]+sh[3];
      sp[1]=sh[4]+sh[5]+sh[6]+sh[7];
      sp[2]=min(min(sh[8],sh[9]),min(sh[10],sh[11]));
      sp[3]=max(max(sh[12],sh[13]),max(sh[14],sh[15]));
      sp[4]=min(min(sh[16],sh[17]),min(sh[18],sh[19]));
      sp[5]=max(max(sh[20],sh[21]),max(sh[22],sh[23]));
    }
  }
}

// ============ K1: count+scatter (0..63) || pts_lin+partK (64..127) || pos_lin+partFC (128..191)
//                 || gather (192..1215) || valproj (1216..1919) ============
__global__ __launch_bounds__(256) void k1(const float* __restrict__ pf,
                                          const float* __restrict__ imf,
                                          const int* __restrict__ grid,
                                          const float* __restrict__ Wk, const float* __restrict__ bk,
                                          const float* __restrict__ Wfc, const float* __restrict__ bfc,
                                          const float* __restrict__ Wval, const float* __restrict__ bval,
                                          float* __restrict__ ws){
  __shared__ float sA[256], sB[16];
  __shared__ float sctr[4];
  const int t = threadIdx.x, b = blockIdx.x;
  const bool ldsK = (b >= 64 && b < 128);
  const bool ldsV = (b >= 1216);
  if (ldsK){ sA[t] = Wk[t];   if (t < 16) sB[t] = bk[t]; }
  if (ldsV){ sA[t] = Wval[t]; if (t < 16) sB[t] = bval[t]; }
  if (ldsK || ldsV) __syncthreads();

  if (b < 64){
    const int i = b*256 + t;
    int2 g = ((const int2*)grid)[i];
    int* counts = (int*)(ws + KNNI_);
    unsigned* slots = (unsigned*)(counts + 180224);
    int cell = g.x*W_ + g.y;
    int pos = atomicAdd(&counts[cell], 1);
    if (pos < 8)
      slots[(ull)cell*8 + pos] = ((unsigned)g.x<<24) | ((unsigned)g.y<<14) | (unsigned)i;
  } else if (ldsK){
    const int i = (b-64)*256 + t;
    float p[16]; LOAD16(p, pf + i*16);
    float ok[16];
#pragma unroll
    for (int c=0;c<16;++c) ok[c] = sB[c];
#pragma unroll
    for (int j=0;j<16;++j){ float v = p[j];
#pragma unroll
      for (int c=0;c<16;++c) ok[c] += v*sA[j*16+c];
    }
    STORE16(ws + HDR_ + i*16, ok);
    float* partK = ws + PARTK_;
    const int grp = i >> 6;
#pragma unroll
    for (int c=0;c<16;++c){
      float a = wsum64(ok[c]); float q2 = wsum64(ok[c]*ok[c]);
      if ((t&63)==0){ partK[grp*32+c]=a; partK[grp*32+16+c]=q2; }
    }
  } else if (b < 192){
    // reduce 64 grid-stat partials -> center/scale
    if (t < 64){
      const int* sp = (const int*)ws + SPI_ + t*8;
      int sy=sp[0], sx=sp[1], mny=sp[2], mxy=sp[3], mnx=sp[4], mxx=sp[5];
#pragma unroll
      for (int o=32;o>0;o>>=1){
        sy += __shfl_down(sy,o); sx += __shfl_down(sx,o);
        mny = min(mny,__shfl_down(mny,o)); mxy = max(mxy,__shfl_down(mxy,o));
        mnx = min(mnx,__shfl_down(mnx,o)); mxx = max(mxx,__shfl_down(mxx,o));
      }
      if (t == 0){
        float cy = (float)sy / (float)N_;
        float cx = (float)sx / (float)N_;
        float my = fmaxf((float)mxy-cy, cy-(float)mny); if (my==0.f) my=1.f;
        float mx = fmaxf((float)mxx-cx, cx-(float)mnx); if (mx==0.f) mx=1.f;
        sctr[0]=cy; sctr[1]=cx; sctr[2]=1.f/my; sctr[3]=1.f/mx;
      }
    }
    __syncthreads();
    const int i = (b-128)*256 + t;
    float cy=sctr[0], cx=sctr[1], imy=sctr[2], imx=sctr[3];
    int2 g = ((const int2*)grid)[i];
    float ry = ((float)g.x - cy)*imy, rx = ((float)g.y - cx)*imx;
    float op[16];
#pragma unroll
    for (int c=0;c<16;++c) op[c] = ry*Wfc[c] + rx*Wfc[16+c] + bfc[c];
    STORE16(ws + HDR_ + NC_ + i*16, op);
    float* partFC = ws + PARTFC_;
    const int grp = i >> 6;
#pragma unroll
    for (int c=0;c<16;++c){
      float a = wsum64(op[c]); float q2 = wsum64(op[c]*op[c]);
      if ((t&63)==0){ partFC[grp*32+c]=a; partFC[grp*32+16+c]=q2; }
    }
  } else if (b < 1216){
    const int idx = (b-192)*256 + t;     // 0..262143
    const int i = idx >> 4, c = idx & 15;
    int2 g = ((const int2*)grid)[i];
    ws[HDR_ + 2*NC_ + idx] = imf[c*HW_ + g.x*W_ + g.y];
  } else {
    const int pix = (b-1216)*256 + t;    // 0..180223
    float a[16];
#pragma unroll
    for (int ci=0;ci<16;++ci) a[ci] = imf[ci*HW_ + pix];
    float o[16];
#pragma unroll
    for (int c=0;c<16;++c) o[c] = sB[c];
#pragma unroll
    for (int ci=0;ci<16;++ci){ float v=a[ci];
#pragma unroll
      for (int c=0;c<16;++c) o[c] += v*sA[ci*16+c];
    }
    STORE16(ws + VAL_ + pix*16, o);
  }
}

// ============ K2: KNN+neigh (0..255) || t_lin+partT (256..319) || off/attn proj (320..383) ============
__global__ __launch_bounds__(256) void k2(const int* __restrict__ grid,
                                          const float* __restrict__ Wt, const float* __restrict__ bt,
                                          const float* __restrict__ gk, const float* __restrict__ betak,
                                          const float* __restrict__ gfc, const float* __restrict__ betafc,
                                          const float* __restrict__ WoffW, const float* __restrict__ boffW,
                                          const float* __restrict__ Wattn, const float* __restrict__ battn,
                                          float* __restrict__ ws){
  const int t = threadIdx.x, b = blockIdx.x;
  __shared__ float sWt[256], sWoff[512], sWattn[256], sboff[32], sbattn[16];
  __shared__ float red[256], coefA[32], coefB[32];
  if (b < 256){
    const int* counts = (const int*)(ws + KNNI_);
    const unsigned* slots = (const unsigned*)(counts + 180224);
    const int lane = t & 63;
    const int s = t & 3, pl = t >> 2;
    const int i = b*64 + pl;
    int2 g = ((const int2*)grid)[i];
    int y = g.x, x = g.y;
    int r = 8;
    { int y0=max(y-8,0),y1=min(y+8,H_-1),x0=max(x-8,0),x1=min(x+8,W_-1);
      if ((y1-y0+1)*(x1-x0+1) < 224) r = 16; }
    ull arr[9];
#pragma unroll
    for (int q=0;q<9;++q) arr[q] = ~0ull;
    {
      int y0=max(y-r,0),y1=min(y+r,H_-1),x0=max(x-r,0),x1=min(x+r,W_-1);
      scan_box_padded(counts, slots, y, x, s, y0, y1, x0, x1, arr);
    }
    ull m[9];
    bool done = false;
    {
      ull k[9];
#pragma unroll
      for (int q=0;q<9;++q) m[q] = ~0ull;
      int base = lane & ~3;
      for (int ss=0; ss<4; ++ss){
#pragma unroll
        for (int q=0;q<9;++q) k[q] = __shfl(arr[q], base+ss);
        for (int q2=0;q2<9;++q2){
          ull kk = k[q2];
          if (kk >= m[8]) break;
          int q = 8; while (q>0 && m[q-1]>kk){ m[q]=m[q-1]; --q; } m[q]=kk;
        }
      }
      int y0=max(y-r,0),y1=min(y+r,H_-1),x0=max(x-r,0),x1=min(x+r,W_-1);
      bool covered = (y0==0)&&(y1==H_-1)&&(x0==0)&&(x1==W_-1);
      bool ok2 = covered;
      if (!ok2 && m[8] != ~0ull){ int d9 = (int)(m[8]>>14); ok2 = d9 < (r+1)*(r+1); }
      done = ok2;
    }
    while (__ballot(!done)){
      if (!done){
        r <<= 1;
        int y0=max(y-r,0),y1=min(y+r,H_-1),x0=max(x-r,0),x1=min(x+r,W_-1);
#pragma unroll
        for (int q=0;q<9;++q) arr[q] = ~0ull;
        scan_box_padded(counts, slots, y, x, s, y0, y1, x0, x1, arr);
      }
      ull k[9];
      bool doIns = !done;
      if (doIns){
#pragma unroll
        for (int q=0;q<9;++q) m[q] = ~0ull;
      }
      int base = lane & ~3;
      for (int ss=0; ss<4; ++ss){
#pragma unroll
        for (int q=0;q<9;++q) k[q] = __shfl(arr[q], base+ss);
        if (doIns){
          for (int q2=0;q2<9;++q2){
            ull kk = k[q2];
            if (kk >= m[8]) break;
            int q = 8; while (q>0 && m[q-1]>kk){ m[q]=m[q-1]; --q; } m[q]=kk;
          }
        }
      }
      if (!done){
        int y0=max(y-r,0),y1=min(y+r,H_-1),x0=max(x-r,0),x1=min(x+r,W_-1);
        bool covered = (y0==0)&&(y1==H_-1)&&(x0==0)&&(x1==W_-1);
        bool ok2 = covered || (r > 1024);   // hard cap: at r>1024 the clipped box IS the grid
        if (!ok2 && m[8] != ~0ull){ int d9 = (int)(m[8]>>14); ok2 = d9 < (r+1)*(r+1); }
        if (ok2) done = true;
      }
    }
    const float* gath = ws + HDR_ + 2*NC_;
    float4 acc = make_float4(0.f,0.f,0.f,0.f);
#pragma unroll
    for (int nb=1; nb<9; ++nb){
      int idx = (int)(m[nb] & 16383ull);
      const float4 g4 = *(const float4*)(gath + idx*16 + s*4);
      acc.x += g4.x; acc.y += g4.y; acc.z += g4.z; acc.w += g4.w;
    }
    float* neigh = ws + HDR_ + 7*NC_;
    *(float4*)(neigh + i*16 + s*4) =
        make_float4(acc.x*0.125f, acc.y*0.125f, acc.z*0.125f, acc.w*0.125f);
  } else if (b < 320){
    sWt[t] = Wt[t];
    __syncthreads();
    red_body(gk, betak, ws + PARTK_, coefA, red);   // kA/kC in coefA
    const int i = (b-256)*256 + t;
    float pl[16]; LOAD16(pl, ws + HDR_ + i*16);
    float pts[16];
#pragma unroll
    for (int c=0;c<16;++c) pts[c] = pl[c]*coefA[c] + coefA[16+c];
    float tv[16];
#pragma unroll
    for (int c=0;c<16;++c) tv[c] = bt[c];
#pragma unroll
    for (int j=0;j<16;++j){ float v = pts[j];
#pragma unroll
      for (int c=0;c<16;++c) tv[c] += v*sWt[j*16+c];
    }
    STORE16(ws + HDR_ + 3*NC_ + i*16, tv);
    float* partT = ws + PARTT_;
    const int grp = i >> 6;
#pragma unroll
    for (int c=0;c<16;++c){
      float a = wsum64(tv[c]); float q2 = wsum64(tv[c]*tv[c]);
      if ((t&63)==0){ partT[grp*32+c]=a; partT[grp*32+16+c]=q2; }
    }
  } else {
    sWoff[t] = WoffW[t]; sWoff[256+t] = WoffW[256+t];
    sWattn[t] = Wattn[t];
    if (t < 32) sboff[t] = boffW[t];
    if (t < 16) sbattn[t] = battn[t];
    __syncthreads();
    red_body(gk, betak, ws + PARTK_, coefA, red);
    red_body(gfc, betafc, ws + PARTFC_, coefB, red);
    const int i = (b-320)*256 + t;
    float pl[16], po[16];
    LOAD16(pl, ws + HDR_ + i*16);
    LOAD16(po, ws + HDR_ + NC_ + i*16);
    float q[16];
#pragma unroll
    for (int c=0;c<16;++c)
      q[c] = pl[c]*coefA[c]+coefA[16+c] + po[c]*coefB[c]+coefB[16+c];
    float ov[32];
#pragma unroll
    for (int o=0;o<32;++o) ov[o] = sboff[o];
#pragma unroll
    for (int j=0;j<16;++j){ float v=q[j];
#pragma unroll
      for (int o=0;o<32;++o) ov[o] += v*sWoff[j*32+o];
    }
    { float4* d=(float4*)(ws + HDR_ + 4*NC_ + i*32);
#pragma unroll
      for (int rr=0;rr<8;++rr) d[rr]=make_float4(ov[rr*4],ov[rr*4+1],ov[rr*4+2],ov[rr*4+3]);
    }
    float l[16];
#pragma unroll
    for (int c=0;c<16;++c) l[c] = sbattn[c];
#pragma unroll
    for (int j=0;j<16;++j){ float v=q[j];
#pragma unroll
      for (int c=0;c<16;++c) l[c] += v*sWattn[j*16+c];
    }
    float av[16];
#pragma unroll
    for (int h=0;h<4;++h){
      float m = fmaxf(fmaxf(l[h*4],l[h*4+1]),fmaxf(l[h*4+2],l[h*4+3]));
      float e0=expf(l[h*4]-m), e1=expf(l[h*4+1]-m), e2=expf(l[h*4+2]-m), e3=expf(l[h*4+3]-m);
      float inv = 1.f/(e0+e1+e2+e3);
      av[h*4]=e0*inv; av[h*4+1]=e1*inv; av[h*4+2]=e2*inv; av[h*4+3]=e3*inv;
    }
    STORE16(ws + HDR_ + 6*NC_ + i*16, av);
  }
}

// ============ K3: deformable attn + Wout + fuse matmul + f-stats (256 blocks) ============
__global__ __launch_bounds__(256) void k3(
    const int* __restrict__ grid,
    const float* __restrict__ Wout, const float* __restrict__ bout,
    const float* __restrict__ Wf, const float* __restrict__ bf,
    const float* __restrict__ gt, const float* __restrict__ betat,
    float* __restrict__ ws)
{
  __shared__ float sWout[256], sWf[512], sbout[16], sbf[16];
  __shared__ float sTl[1024], sNei[1024], sSamp[1024], sImg[1024];
  __shared__ float sPart[128];
  __shared__ float red[256], coefT[32];
  int t = threadIdx.x, b = blockIdx.x;
  int p = t >> 2, h = t & 3;
  int i = b*64 + p;
  sWout[t]=Wout[t]; sWf[t]=Wf[t]; sWf[t+256]=Wf[t+256];
  if (t<16){ sbout[t]=bout[t]; sbf[t]=bf[t]; }
  red_body(gt, betat, ws + PARTT_, coefT, red);
  {
    const float4* tl4 = (const float4*)(ws + HDR_ + 3*NC_ + b*1024);
    const float4* nv4 = (const float4*)(ws + HDR_ + 7*NC_ + b*1024);
    float4 v = tl4[t];
    int c0 = (t*4) & 15;
    float a0=coefT[c0],a1=coefT[c0+1],a2=coefT[c0+2],a3=coefT[c0+3];
    float c0v=coefT[16+c0],c1v=coefT[17+c0],c2v=coefT[18+c0],c3v=coefT[19+c0];
    sTl[t*4]   = fmaxf(v.x*a0+c0v, 0.f);
    sTl[t*4+1] = fmaxf(v.y*a1+c1v, 0.f);
    sTl[t*4+2] = fmaxf(v.z*a2+c2v, 0.f);
    sTl[t*4+3] = fmaxf(v.w*a3+c3v, 0.f);
    float4 nv = nv4[t];
    sNei[t*4]=nv.x; sNei[t*4+1]=nv.y; sNei[t*4+2]=nv.z; sNei[t*4+3]=nv.w;
  }
  const float4* off4 = (const float4*)(ws + HDR_ + 4*NC_ + b*2048);
  float4 o0 = off4[t*2], o1 = off4[t*2+1];
  float4 aw = ((const float4*)(ws + HDR_ + 6*NC_ + b*1024))[t];
  int2 g = ((const int2*)grid)[i];
  float y = (float)g.x, x = (float)g.y;
  const float4* val4 = (const float4*)(ws + VAL_);
  float4 acc = make_float4(0.f,0.f,0.f,0.f);
  float offv[8] = {o0.x,o0.y,o0.z,o0.w,o1.x,o1.y,o1.z,o1.w};
  float avv[4]  = {aw.x,aw.y,aw.z,aw.w};
#define CORNER(yy,xx,wgt) do{ int _y=(yy),_x=(xx); \
    if ((unsigned)_y < (unsigned)H_ && (unsigned)_x < (unsigned)W_){ \
      float4 _v = val4[(_y*W_+_x)*4 + h]; float _w = a*(wgt); \
      acc.x += _w*_v.x; acc.y += _w*_v.y; acc.z += _w*_v.z; acc.w += _w*_v.w; } }while(0)
#pragma unroll
  for (int pt=0; pt<4; ++pt){
    float a  = avv[pt];
    float ly = y + offv[pt*2], lx = x + offv[pt*2+1];
    float fy = floorf(ly), fx = floorf(lx);
    float wy = ly - fy, wx = lx - fx;
    int y0 = (int)fy, x0 = (int)fx;
    CORNER(y0,   x0,   (1.f-wy)*(1.f-wx));
    CORNER(y0,   x0+1, (1.f-wy)*wx);
    CORNER(y0+1, x0,   wy*(1.f-wx));
    CORNER(y0+1, x0+1, wy*wx);
  }
#undef CORNER
  ((float4*)sSamp)[t] = acc;
  __syncthreads();
  float img[4];
#pragma unroll
  for (int k=0;k<4;++k){ int cc=h*4+k; img[k] = sbout[cc] + sNei[p*16+cc]; }
#pragma unroll
  for (int j=0;j<16;++j){
    float v = sSamp[p*16+j];
#pragma unroll
    for (int k=0;k<4;++k) img[k] += v*sWout[j*16 + h*4 + k];
  }
  ((float4*)sImg)[t] = make_float4(img[0],img[1],img[2],img[3]);
  __syncthreads();
  float fl[4];
#pragma unroll
  for (int k=0;k<4;++k) fl[k] = sbf[h*4+k];
#pragma unroll
  for (int j=0;j<16;++j){
    float v1 = sTl[p*16+j];
    float v2 = fmaxf(sImg[p*16+j], 0.f);
#pragma unroll
    for (int k=0;k<4;++k){
      fl[k] += v1*sWf[j*16 + h*4 + k];
      fl[k] += v2*sWf[(16+j)*16 + h*4 + k];
    }
  }
  float* f_lin = ws + HDR_ + 8*NC_;
  ((float4*)(f_lin + b*1024))[t] = make_float4(fl[0],fl[1],fl[2],fl[3]);
  float s0=fl[0],s1=fl[1],s2=fl[2],s3=fl[3];
  float q0=fl[0]*fl[0],q1=fl[1]*fl[1],q2=fl[2]*fl[2],q3=fl[3]*fl[3];
#pragma unroll
  for (int o=32;o>=4;o>>=1){
    s0+=__shfl_down(s0,o); s1+=__shfl_down(s1,o); s2+=__shfl_down(s2,o); s3+=__shfl_down(s3,o);
    q0+=__shfl_down(q0,o); q1+=__shfl_down(q1,o); q2+=__shfl_down(q2,o); q3+=__shfl_down(q3,o);
  }
  int wave = t >> 6, lane = t & 63;
  if (lane < 4){
    sPart[wave*32 + lane*4+0]=s0; sPart[wave*32 + lane*4+1]=s1;
    sPart[wave*32 + lane*4+2]=s2; sPart[wave*32 + lane*4+3]=s3;
    sPart[wave*32 + 16 + lane*4+0]=q0; sPart[wave*32 + 16 + lane*4+1]=q1;
    sPart[wave*32 + 16 + lane*4+2]=q2; sPart[wave*32 + 16 + lane*4+3]=q3;
  }
  __syncthreads();
  if (t < 32){
    float v = sPart[t]+sPart[32+t]+sPart[64+t]+sPart[96+t];
    (ws + PARTF2_)[b*32 + t] = v;
  }
}

// ============ K4: output (256 blocks) ============
__global__ __launch_bounds__(256) void k4(const float* __restrict__ gf, const float* __restrict__ betaf,
                                          float* __restrict__ ws, float* __restrict__ out){
  __shared__ float red[256], coefF[32];
  red_body(gf, betaf, ws + PARTF2_, coefF, red);
  const int gtid = blockIdx.x*256 + threadIdx.x;
  const int idx4 = gtid*4;
  float4 v = *(const float4*)(ws + HDR_ + 8*NC_ + idx4);
  const int c = idx4 & 15;
  float4 r;
  r.x = fmaxf(v.x*coefF[c]   + coefF[16+c],   0.f);
  r.y = fmaxf(v.y*coefF[c+1] + coefF[17+c],   0.f);
  r.z = fmaxf(v.z*coefF[c+2] + coefF[18+c],   0.f);
  r.w = fmaxf(v.w*coefF[c+3] + coefF[19+c],   0.f);
  *(float4*)(out + idx4) = r;
}

extern "C" void kernel_launch(void* const* d_in, const int* in_sizes, int n_in,
                              void* d_out, int out_size, void* d_ws, size_t ws_size,
                              hipStream_t stream)
{
  (void)in_sizes; (void)n_in; (void)out_size; (void)ws_size;
  const float* pf    = (const float*)d_in[0];
  const float* imf   = (const float*)d_in[1];
  const int*   gridp = (const int*)d_in[2];
  const float* Wk   =(const float*)d_in[3],  *bk   =(const float*)d_in[4];
  const float* gk   =(const float*)d_in[5],  *betak=(const float*)d_in[6];
  const float* Wfc  =(const float*)d_in[7],  *bfc  =(const float*)d_in[8];
  const float* gfc  =(const float*)d_in[9],  *betafc=(const float*)d_in[10];
  const float* Wt   =(const float*)d_in[11], *bt   =(const float*)d_in[12];
  const float* gt   =(const float*)d_in[13], *betat=(const float*)d_in[14];
  const float* Woff =(const float*)d_in[15], *boff =(const float*)d_in[16];
  const float* Wattn=(const float*)d_in[17], *battn=(const float*)d_in[18];
  const float* Wval =(const float*)d_in[19], *bval =(const float*)d_in[20];
  const float* Wout =(const float*)d_in[21], *bout =(const float*)d_in[22];
  const float* Wf   =(const float*)d_in[23], *bf   =(const float*)d_in[24];
  const float* gf   =(const float*)d_in[25], *betaf=(const float*)d_in[26];
  float* ws  = (float*)d_ws;
  float* out = (float*)d_out;

  hipLaunchKernelGGL(k0, dim3(240),  dim3(256), 0, stream, gridp, ws);
  hipLaunchKernelGGL(k1, dim3(1920), dim3(256), 0, stream, pf, imf, gridp, Wk, bk, Wfc, bfc, Wval, bval, ws);
  hipLaunchKernelGGL(k2, dim3(384),  dim3(256), 0, stream, gridp, Wt, bt, gk, betak, gfc, betafc, Woff, boff, Wattn, battn, ws);
  hipLaunchKernelGGL(k3, dim3(256),  dim3(256), 0, stream, gridp, Wout, bout, Wf, bf, gt, betat, ws);
  hipLaunchKernelGGL(k4, dim3(256),  dim3(256), 0, stream, gf, betaf, ws, out);
}

// Round 7
// 245.081 us; speedup vs baseline: 1.2367x; 1.2367x over previous
//
#include <hip/hip_runtime.h>
#include <climits>

#define N_ 16384
#define H_ 256
#define W_ 704
#define HW_ (H_*W_)
#define NC_ (N_*16)
#define EPS_ 1e-3f
#define HDR_ 512

typedef unsigned long long ull;

// ---- workspace layout (float units) ----
// arrays at HDR_: pts_lin(0) pos_lin(1) gath(2) t_lin(3) off(4,5) attn(6) neigh(7) f_lin(8) val(9..)
#define VAL_    (HDR_ + 9*NC_)
#define KNNI_   (VAL_ + HW_*16)          // counts: 180224 ints, then slots: 180224*8 u32
#define PARTK_  (KNNI_ + 1622016)        // 256x32 floats
#define PARTFC_ (PARTK_ + 8192)
#define PARTT_  (PARTK_ + 16384)
#define PARTF2_ (PARTK_ + 24576)
#define SPI_    (PARTK_ + 32768)         // int offset: 64 blocks x 8 ints grid-stat partials

__device__ __forceinline__ float wsum64(float v){
#pragma unroll
  for (int o = 32; o > 0; o >>= 1) v += __shfl_down(v, o);
  return v;
}

#define LOAD16(dst, src) { const float4* _s=(const float4*)(src); float4 _a=_s[0],_b=_s[1],_c=_s[2],_d=_s[3]; \
  dst[0]=_a.x;dst[1]=_a.y;dst[2]=_a.z;dst[3]=_a.w; dst[4]=_b.x;dst[5]=_b.y;dst[6]=_b.z;dst[7]=_b.w; \
  dst[8]=_c.x;dst[9]=_c.y;dst[10]=_c.z;dst[11]=_c.w; dst[12]=_d.x;dst[13]=_d.y;dst[14]=_d.z;dst[15]=_d.w; }

#define STORE16(dst, src) { float4* _d=(float4*)(dst); \
  _d[0]=make_float4(src[0],src[1],src[2],src[3]); _d[1]=make_float4(src[4],src[5],src[6],src[7]); \
  _d[2]=make_float4(src[8],src[9],src[10],src[11]); _d[3]=make_float4(src[12],src[13],src[14],src[15]); }

__device__ __forceinline__ void knn_insert(ull* arr, ull key){
  if (key < arr[8]){
    int q = 8;
    while (q > 0 && arr[q-1] > key){ arr[q] = arr[q-1]; --q; }
    arr[q] = key;
  }
}

// enumerate candidates from padded cell table; lane gl (0..15) handles rows y0+gl, stride 16.
// R7: 16 lanes per point (was 4) — shorter per-lane chain, 4x the waves for latency hiding.
__device__ __forceinline__ void scan_box16(const int* __restrict__ counts,
                                           const unsigned* __restrict__ slots,
                                           int y, int x, int gl,
                                           int y0, int y1, int x0, int x1, ull* arr){
  for (int yy=y0+gl; yy<=y1; yy+=16){
    const int rowb = yy*W_;
    const int dy = y-yy, dy2 = dy*dy;
    for (int xx=x0; xx<=x1; ++xx){
      int c = counts[rowb+xx];
      if (c){
        c = min(c, 8);
        const unsigned* sl = slots + (ull)(rowb+xx)*8;
        const int dx = x-xx;
        const ull base = ((ull)(unsigned)(dy2 + dx*dx)) << 14;
        for (int k=0;k<c;++k)
          knn_insert(arr, base | (ull)(sl[k] & 16383u));
      }
    }
  }
}

// reduce 256x32 partials -> BN affine coefs into LDS (whole block participates)
__device__ __forceinline__ void red_body(const float* __restrict__ g, const float* __restrict__ bta,
                                         const float* __restrict__ part, float* __restrict__ coef,
                                         float* __restrict__ red){
  int t = threadIdx.x, slot = t & 31, chunk = t >> 5;
  float acc = 0.f;
  for (int bb=chunk*32; bb<chunk*32+32; ++bb) acc += part[bb*32 + slot];
  red[t] = acc;
  __syncthreads();
  if (chunk == 0){
    float v = red[slot];
#pragma unroll
    for (int k2=1;k2<8;++k2) v += red[k2*32+slot];
    red[slot] = v;
  }
  __syncthreads();
  if (t < 16){
    float mu  = red[t]    * (1.f/N_);
    float var = red[16+t] * (1.f/N_) - mu*mu;
    float a = g[t] / sqrtf(var + EPS_);
    coef[t]    = a;
    coef[16+t] = bta[t] - mu*a;
  }
  __syncthreads();
}

// ============ K0: zero cell counts (0..175) || grid-stat partials (176..239) ============
__global__ __launch_bounds__(256) void k0(const int* __restrict__ grid, float* __restrict__ ws){
  const int t = threadIdx.x, b = blockIdx.x;
  if (b < 176){
    int4* c4 = (int4*)(ws + KNNI_);
    c4[b*256 + t] = make_int4(0,0,0,0);
  } else {
    const int sb = b - 176;
    int2 p = ((const int2*)grid)[sb*256 + t];
    int sy=p.x, sx=p.y, mny=p.x, mxy=p.x, mnx=p.y, mxx=p.y;
#pragma unroll
    for (int o=32;o>0;o>>=1){
      sy += __shfl_down(sy,o); sx += __shfl_down(sx,o);
      mny = min(mny,__shfl_down(mny,o)); mxy = max(mxy,__shfl_down(mxy,o));
      mnx = min(mnx,__shfl_down(mnx,o)); mxx = max(mxx,__shfl_down(mxx,o));
    }
    __shared__ int sh[24];
    int w = t >> 6;
    if ((t & 63) == 0){
      sh[w]=sy; sh[4+w]=sx; sh[8+w]=mny; sh[12+w]=mxy; sh[16+w]=mnx; sh[20+w]=mxx;
    }
    __syncthreads();
    if (t == 0){
      int* sp = (int*)ws + SPI_ + sb*8;
      sp[0]=sh[0]+sh[1]+sh[2]+sh[3];
      sp[1]=sh[4]+sh[5]+sh[6]+sh[7];
      sp[2]=min(min(sh[8],sh[9]),min(sh[10],sh[11]));
      sp[3]=max(max(sh[12],sh[13]),max(sh[14],sh[15]));
      sp[4]=min(min(sh[16],sh[17]),min(sh[18],sh[19]));
      sp[5]=max(max(sh[20],sh[21]),max(sh[22],sh[23]));
    }
  }
}

// ============ K1: count+scatter (0..63) || pts_lin+partK (64..127) || pos_lin+partFC (128..191)
//                 || gather (192..1215) || valproj (1216..1919) ============
__global__ __launch_bounds__(256) void k1(const float* __restrict__ pf,
                                          const float* __restrict__ imf,
                                          const int* __restrict__ grid,
                                          const float* __restrict__ Wk, const float* __restrict__ bk,
                                          const float* __restrict__ Wfc, const float* __restrict__ bfc,
                                          const float* __restrict__ Wval, const float* __restrict__ bval,
                                          float* __restrict__ ws){
  __shared__ float sA[256], sB[16];
  __shared__ float sctr[4];
  const int t = threadIdx.x, b = blockIdx.x;
  const bool ldsK = (b >= 64 && b < 128);
  const bool ldsV = (b >= 1216);
  if (ldsK){ sA[t] = Wk[t];   if (t < 16) sB[t] = bk[t]; }
  if (ldsV){ sA[t] = Wval[t]; if (t < 16) sB[t] = bval[t]; }
  if (ldsK || ldsV) __syncthreads();

  if (b < 64){
    const int i = b*256 + t;
    int2 g = ((const int2*)grid)[i];
    int* counts = (int*)(ws + KNNI_);
    unsigned* slots = (unsigned*)(counts + 180224);
    int cell = g.x*W_ + g.y;
    int pos = atomicAdd(&counts[cell], 1);
    if (pos < 8)
      slots[(ull)cell*8 + pos] = ((unsigned)g.x<<24) | ((unsigned)g.y<<14) | (unsigned)i;
  } else if (ldsK){
    const int i = (b-64)*256 + t;
    float p[16]; LOAD16(p, pf + i*16);
    float ok[16];
#pragma unroll
    for (int c=0;c<16;++c) ok[c] = sB[c];
#pragma unroll
    for (int j=0;j<16;++j){ float v = p[j];
#pragma unroll
      for (int c=0;c<16;++c) ok[c] += v*sA[j*16+c];
    }
    STORE16(ws + HDR_ + i*16, ok);
    float* partK = ws + PARTK_;
    const int grp = i >> 6;
#pragma unroll
    for (int c=0;c<16;++c){
      float a = wsum64(ok[c]); float q2 = wsum64(ok[c]*ok[c]);
      if ((t&63)==0){ partK[grp*32+c]=a; partK[grp*32+16+c]=q2; }
    }
  } else if (b < 192){
    // reduce 64 grid-stat partials -> center/scale
    if (t < 64){
      const int* sp = (const int*)ws + SPI_ + t*8;
      int sy=sp[0], sx=sp[1], mny=sp[2], mxy=sp[3], mnx=sp[4], mxx=sp[5];
#pragma unroll
      for (int o=32;o>0;o>>=1){
        sy += __shfl_down(sy,o); sx += __shfl_down(sx,o);
        mny = min(mny,__shfl_down(mny,o)); mxy = max(mxy,__shfl_down(mxy,o));
        mnx = min(mnx,__shfl_down(mnx,o)); mxx = max(mxx,__shfl_down(mxx,o));
      }
      if (t == 0){
        float cy = (float)sy / (float)N_;
        float cx = (float)sx / (float)N_;
        float my = fmaxf((float)mxy-cy, cy-(float)mny); if (my==0.f) my=1.f;
        float mx = fmaxf((float)mxx-cx, cx-(float)mnx); if (mx==0.f) mx=1.f;
        sctr[0]=cy; sctr[1]=cx; sctr[2]=1.f/my; sctr[3]=1.f/mx;
      }
    }
    __syncthreads();
    const int i = (b-128)*256 + t;
    float cy=sctr[0], cx=sctr[1], imy=sctr[2], imx=sctr[3];
    int2 g = ((const int2*)grid)[i];
    float ry = ((float)g.x - cy)*imy, rx = ((float)g.y - cx)*imx;
    float op[16];
#pragma unroll
    for (int c=0;c<16;++c) op[c] = ry*Wfc[c] + rx*Wfc[16+c] + bfc[c];
    STORE16(ws + HDR_ + NC_ + i*16, op);
    float* partFC = ws + PARTFC_;
    const int grp = i >> 6;
#pragma unroll
    for (int c=0;c<16;++c){
      float a = wsum64(op[c]); float q2 = wsum64(op[c]*op[c]);
      if ((t&63)==0){ partFC[grp*32+c]=a; partFC[grp*32+16+c]=q2; }
    }
  } else if (b < 1216){
    const int idx = (b-192)*256 + t;     // 0..262143
    const int i = idx >> 4, c = idx & 15;
    int2 g = ((const int2*)grid)[i];
    ws[HDR_ + 2*NC_ + idx] = imf[c*HW_ + g.x*W_ + g.y];
  } else {
    const int pix = (b-1216)*256 + t;    // 0..180223
    float a[16];
#pragma unroll
    for (int ci=0;ci<16;++ci) a[ci] = imf[ci*HW_ + pix];
    float o[16];
#pragma unroll
    for (int c=0;c<16;++c) o[c] = sB[c];
#pragma unroll
    for (int ci=0;ci<16;++ci){ float v=a[ci];
#pragma unroll
      for (int c=0;c<16;++c) o[c] += v*sA[ci*16+c];
    }
    STORE16(ws + VAL_ + pix*16, o);
  }
}

// ============ K2: KNN+neigh (0..1023, 16 pts/block, 16 lanes/pt)
//                 || t_lin+partT (1024..1087) || off/attn proj (1088..1151) ============
__global__ __launch_bounds__(256) void k2(const int* __restrict__ grid,
                                          const float* __restrict__ Wt, const float* __restrict__ bt,
                                          const float* __restrict__ gk, const float* __restrict__ betak,
                                          const float* __restrict__ gfc, const float* __restrict__ betafc,
                                          const float* __restrict__ WoffW, const float* __restrict__ boffW,
                                          const float* __restrict__ Wattn, const float* __restrict__ battn,
                                          float* __restrict__ ws){
  const int t = threadIdx.x, b = blockIdx.x;
  __shared__ float sWt[256], sWoff[512], sWattn[256], sboff[32], sbattn[16];
  __shared__ float red[256], coefA[32], coefB[32];
  if (b < 1024){
    const int* counts = (const int*)(ws + KNNI_);
    const unsigned* slots = (const unsigned*)(counts + 180224);
    const int lane = t & 63;
    const int gl = t & 15;          // lane within the 16-lane point-group
    const int pg = t >> 4;          // point within block (0..15)
    const int i = b*16 + pg;
    int2 g = ((const int2*)grid)[i];
    int y = g.x, x = g.y;
    int r = 8;
    { int y0=max(y-8,0),y1=min(y+8,H_-1),x0=max(x-8,0),x1=min(x+8,W_-1);
      if ((y1-y0+1)*(x1-x0+1) < 224) r = 16; }
    ull arr[9];
#pragma unroll
    for (int q=0;q<9;++q) arr[q] = ~0ull;
    {
      int y0=max(y-r,0),y1=min(y+r,H_-1),x0=max(x-r,0),x1=min(x+r,W_-1);
      scan_box16(counts, slots, y, x, gl, y0, y1, x0, x1, arr);
    }
    // 16-lane XOR-butterfly merge of sorted 9-lists (uniform shuffles)
    ull m[9];
    bool done = false;
    {
#pragma unroll
      for (int q=0;q<9;++q) m[q] = arr[q];
#pragma unroll
      for (int o=1;o<16;o<<=1){
        ull k[9];
        int src = (lane & 48) | ((lane & 15) ^ o);
#pragma unroll
        for (int q=0;q<9;++q) k[q] = __shfl(m[q], src);
        for (int q2=0;q2<9;++q2){
          ull kk = k[q2];
          if (kk >= m[8]) break;
          int q = 8; while (q>0 && m[q-1]>kk){ m[q]=m[q-1]; --q; } m[q]=kk;
        }
      }
      int y0=max(y-r,0),y1=min(y+r,H_-1),x0=max(x-r,0),x1=min(x+r,W_-1);
      bool covered = (y0==0)&&(y1==H_-1)&&(x0==0)&&(x1==W_-1);
      bool ok2 = covered;
      if (!ok2 && m[8] != ~0ull){ int d9 = (int)(m[8]>>14); ok2 = d9 < (r+1)*(r+1); }
      done = ok2;
    }
    // rare retries: wave-uniform loop; shuffles outside divergence
    while (__ballot(!done)){
      if (!done){
        r <<= 1;
        int y0=max(y-r,0),y1=min(y+r,H_-1),x0=max(x-r,0),x1=min(x+r,W_-1);
#pragma unroll
        for (int q=0;q<9;++q) arr[q] = ~0ull;
        scan_box16(counts, slots, y, x, gl, y0, y1, x0, x1, arr);
      }
      bool doIns = !done;
      if (doIns){
#pragma unroll
        for (int q=0;q<9;++q) m[q] = arr[q];
      }
#pragma unroll
      for (int o=1;o<16;o<<=1){
        ull k[9];
        int src = (lane & 48) | ((lane & 15) ^ o);
#pragma unroll
        for (int q=0;q<9;++q) k[q] = __shfl(m[q], src);
        if (doIns){
          for (int q2=0;q2<9;++q2){
            ull kk = k[q2];
            if (kk >= m[8]) break;
            int q = 8; while (q>0 && m[q-1]>kk){ m[q]=m[q-1]; --q; } m[q]=kk;
          }
        }
      }
      if (!done){
        int y0=max(y-r,0),y1=min(y+r,H_-1),x0=max(x-r,0),x1=min(x+r,W_-1);
        bool covered = (y0==0)&&(y1==H_-1)&&(x0==0)&&(x1==W_-1);
        bool ok2 = covered || (r > 1024);   // hard cap: at r>1024 the clipped box IS the grid
        if (!ok2 && m[8] != ~0ull){ int d9 = (int)(m[8]>>14); ok2 = d9 < (r+1)*(r+1); }
        if (ok2) done = true;
      }
    }
    // neighbor-feature mean: lanes 0..3 of each group gather float4 quarters
    if (gl < 4){
      const float* gath = ws + HDR_ + 2*NC_;
      float4 acc = make_float4(0.f,0.f,0.f,0.f);
#pragma unroll
      for (int nb=1; nb<9; ++nb){
        int idx = (int)(m[nb] & 16383ull);
        const float4 g4 = *(const float4*)(gath + idx*16 + gl*4);
        acc.x += g4.x; acc.y += g4.y; acc.z += g4.z; acc.w += g4.w;
      }
      float* neigh = ws + HDR_ + 7*NC_;
      *(float4*)(neigh + i*16 + gl*4) =
          make_float4(acc.x*0.125f, acc.y*0.125f, acc.z*0.125f, acc.w*0.125f);
    }
  } else if (b < 1088){
    sWt[t] = Wt[t];
    __syncthreads();
    red_body(gk, betak, ws + PARTK_, coefA, red);   // kA/kC in coefA
    const int i = (b-1024)*256 + t;
    float pl[16]; LOAD16(pl, ws + HDR_ + i*16);
    float pts[16];
#pragma unroll
    for (int c=0;c<16;++c) pts[c] = pl[c]*coefA[c] + coefA[16+c];
    float tv[16];
#pragma unroll
    for (int c=0;c<16;++c) tv[c] = bt[c];
#pragma unroll
    for (int j=0;j<16;++j){ float v = pts[j];
#pragma unroll
      for (int c=0;c<16;++c) tv[c] += v*sWt[j*16+c];
    }
    STORE16(ws + HDR_ + 3*NC_ + i*16, tv);
    float* partT = ws + PARTT_;
    const int grp = i >> 6;
#pragma unroll
    for (int c=0;c<16;++c){
      float a = wsum64(tv[c]); float q2 = wsum64(tv[c]*tv[c]);
      if ((t&63)==0){ partT[grp*32+c]=a; partT[grp*32+16+c]=q2; }
    }
  } else {
    sWoff[t] = WoffW[t]; sWoff[256+t] = WoffW[256+t];
    sWattn[t] = Wattn[t];
    if (t < 32) sboff[t] = boffW[t];
    if (t < 16) sbattn[t] = battn[t];
    __syncthreads();
    red_body(gk, betak, ws + PARTK_, coefA, red);
    red_body(gfc, betafc, ws + PARTFC_, coefB, red);
    const int i = (b-1088)*256 + t;
    float pl[16], po[16];
    LOAD16(pl, ws + HDR_ + i*16);
    LOAD16(po, ws + HDR_ + NC_ + i*16);
    float q[16];
#pragma unroll
    for (int c=0;c<16;++c)
      q[c] = pl[c]*coefA[c]+coefA[16+c] + po[c]*coefB[c]+coefB[16+c];
    float ov[32];
#pragma unroll
    for (int o=0;o<32;++o) ov[o] = sboff[o];
#pragma unroll
    for (int j=0;j<16;++j){ float v=q[j];
#pragma unroll
      for (int o=0;o<32;++o) ov[o] += v*sWoff[j*32+o];
    }
    { float4* d=(float4*)(ws + HDR_ + 4*NC_ + i*32);
#pragma unroll
      for (int rr=0;rr<8;++rr) d[rr]=make_float4(ov[rr*4],ov[rr*4+1],ov[rr*4+2],ov[rr*4+3]);
    }
    float l[16];
#pragma unroll
    for (int c=0;c<16;++c) l[c] = sbattn[c];
#pragma unroll
    for (int j=0;j<16;++j){ float v=q[j];
#pragma unroll
      for (int c=0;c<16;++c) l[c] += v*sWattn[j*16+c];
    }
    float av[16];
#pragma unroll
    for (int h=0;h<4;++h){
      float m = fmaxf(fmaxf(l[h*4],l[h*4+1]),fmaxf(l[h*4+2],l[h*4+3]));
      float e0=expf(l[h*4]-m), e1=expf(l[h*4+1]-m), e2=expf(l[h*4+2]-m), e3=expf(l[h*4+3]-m);
      float inv = 1.f/(e0+e1+e2+e3);
      av[h*4]=e0*inv; av[h*4+1]=e1*inv; av[h*4+2]=e2*inv; av[h*4+3]=e3*inv;
    }
    STORE16(ws + HDR_ + 6*NC_ + i*16, av);
  }
}

// ============ K3: deformable attn + Wout + fuse matmul + f-stats (256 blocks) ============
__global__ __launch_bounds__(256) void k3(
    const int* __restrict__ grid,
    const float* __restrict__ Wout, const float* __restrict__ bout,
    const float* __restrict__ Wf, const float* __restrict__ bf,
    const float* __restrict__ gt, const float* __restrict__ betat,
    float* __restrict__ ws)
{
  __shared__ float sWout[256], sWf[512], sbout[16], sbf[16];
  __shared__ float sTl[1024], sNei[1024], sSamp[1024], sImg[1024];
  __shared__ float sPart[128];
  __shared__ float red[256], coefT[32];
  int t = threadIdx.x, b = blockIdx.x;
  int p = t >> 2, h = t & 3;
  int i = b*64 + p;
  sWout[t]=Wout[t]; sWf[t]=Wf[t]; sWf[t+256]=Wf[t+256];
  if (t<16){ sbout[t]=bout[t]; sbf[t]=bf[t]; }
  red_body(gt, betat, ws + PARTT_, coefT, red);
  {
    const float4* tl4 = (const float4*)(ws + HDR_ + 3*NC_ + b*1024);
    const float4* nv4 = (const float4*)(ws + HDR_ + 7*NC_ + b*1024);
    float4 v = tl4[t];
    int c0 = (t*4) & 15;
    float a0=coefT[c0],a1=coefT[c0+1],a2=coefT[c0+2],a3=coefT[c0+3];
    float c0v=coefT[16+c0],c1v=coefT[17+c0],c2v=coefT[18+c0],c3v=coefT[19+c0];
    sTl[t*4]   = fmaxf(v.x*a0+c0v, 0.f);
    sTl[t*4+1] = fmaxf(v.y*a1+c1v, 0.f);
    sTl[t*4+2] = fmaxf(v.z*a2+c2v, 0.f);
    sTl[t*4+3] = fmaxf(v.w*a3+c3v, 0.f);
    float4 nv = nv4[t];
    sNei[t*4]=nv.x; sNei[t*4+1]=nv.y; sNei[t*4+2]=nv.z; sNei[t*4+3]=nv.w;
  }
  const float4* off4 = (const float4*)(ws + HDR_ + 4*NC_ + b*2048);
  float4 o0 = off4[t*2], o1 = off4[t*2+1];
  float4 aw = ((const float4*)(ws + HDR_ + 6*NC_ + b*1024))[t];
  int2 g = ((const int2*)grid)[i];
  float y = (float)g.x, x = (float)g.y;
  const float4* val4 = (const float4*)(ws + VAL_);
  float4 acc = make_float4(0.f,0.f,0.f,0.f);
  float offv[8] = {o0.x,o0.y,o0.z,o0.w,o1.x,o1.y,o1.z,o1.w};
  float avv[4]  = {aw.x,aw.y,aw.z,aw.w};
#define CORNER(yy,xx,wgt) do{ int _y=(yy),_x=(xx); \
    if ((unsigned)_y < (unsigned)H_ && (unsigned)_x < (unsigned)W_){ \
      float4 _v = val4[(_y*W_+_x)*4 + h]; float _w = a*(wgt); \
      acc.x += _w*_v.x; acc.y += _w*_v.y; acc.z += _w*_v.z; acc.w += _w*_v.w; } }while(0)
#pragma unroll
  for (int pt=0; pt<4; ++pt){
    float a  = avv[pt];
    float ly = y + offv[pt*2], lx = x + offv[pt*2+1];
    float fy = floorf(ly), fx = floorf(lx);
    float wy = ly - fy, wx = lx - fx;
    int y0 = (int)fy, x0 = (int)fx;
    CORNER(y0,   x0,   (1.f-wy)*(1.f-wx));
    CORNER(y0,   x0+1, (1.f-wy)*wx);
    CORNER(y0+1, x0,   wy*(1.f-wx));
    CORNER(y0+1, x0+1, wy*wx);
  }
#undef CORNER
  ((float4*)sSamp)[t] = acc;
  __syncthreads();
  float img[4];
#pragma unroll
  for (int k=0;k<4;++k){ int cc=h*4+k; img[k] = sbout[cc] + sNei[p*16+cc]; }
#pragma unroll
  for (int j=0;j<16;++j){
    float v = sSamp[p*16+j];
#pragma unroll
    for (int k=0;k<4;++k) img[k] += v*sWout[j*16 + h*4 + k];
  }
  ((float4*)sImg)[t] = make_float4(img[0],img[1],img[2],img[3]);
  __syncthreads();
  float fl[4];
#pragma unroll
  for (int k=0;k<4;++k) fl[k] = sbf[h*4+k];
#pragma unroll
  for (int j=0;j<16;++j){
    float v1 = sTl[p*16+j];
    float v2 = fmaxf(sImg[p*16+j], 0.f);
#pragma unroll
    for (int k=0;k<4;++k){
      fl[k] += v1*sWf[j*16 + h*4 + k];
      fl[k] += v2*sWf[(16+j)*16 + h*4 + k];
    }
  }
  float* f_lin = ws + HDR_ + 8*NC_;
  ((float4*)(f_lin + b*1024))[t] = make_float4(fl[0],fl[1],fl[2],fl[3]);
  float s0=fl[0],s1=fl[1],s2=fl[2],s3=fl[3];
  float q0=fl[0]*fl[0],q1=fl[1]*fl[1],q2=fl[2]*fl[2],q3=fl[3]*fl[3];
#pragma unroll
  for (int o=32;o>=4;o>>=1){
    s0+=__shfl_down(s0,o); s1+=__shfl_down(s1,o); s2+=__shfl_down(s2,o); s3+=__shfl_down(s3,o);
    q0+=__shfl_down(q0,o); q1+=__shfl_down(q1,o); q2+=__shfl_down(q2,o); q3+=__shfl_down(q3,o);
  }
  int wave = t >> 6, lane = t & 63;
  if (lane < 4){
    sPart[wave*32 + lane*4+0]=s0; sPart[wave*32 + lane*4+1]=s1;
    sPart[wave*32 + lane*4+2]=s2; sPart[wave*32 + lane*4+3]=s3;
    sPart[wave*32 + 16 + lane*4+0]=q0; sPart[wave*32 + 16 + lane*4+1]=q1;
    sPart[wave*32 + 16 + lane*4+2]=q2; sPart[wave*32 + 16 + lane*4+3]=q3;
  }
  __syncthreads();
  if (t < 32){
    float v = sPart[t]+sPart[32+t]+sPart[64+t]+sPart[96+t];
    (ws + PARTF2_)[b*32 + t] = v;
  }
}

// ============ K4: output (256 blocks) ============
__global__ __launch_bounds__(256) void k4(const float* __restrict__ gf, const float* __restrict__ betaf,
                                          float* __restrict__ ws, float* __restrict__ out){
  __shared__ float red[256], coefF[32];
  red_body(gf, betaf, ws + PARTF2_, coefF, red);
  const int gtid = blockIdx.x*256 + threadIdx.x;
  const int idx4 = gtid*4;
  float4 v = *(const float4*)(ws + HDR_ + 8*NC_ + idx4);
  const int c = idx4 & 15;
  float4 r;
  r.x = fmaxf(v.x*coefF[c]   + coefF[16+c],   0.f);
  r.y = fmaxf(v.y*coefF[c+1] + coefF[17+c],   0.f);
  r.z = fmaxf(v.z*coefF[c+2] + coefF[18+c],   0.f);
  r.w = fmaxf(v.w*coefF[c+3] + coefF[19+c],   0.f);
  *(float4*)(out + idx4) = r;
}

extern "C" void kernel_launch(void* const* d_in, const int* in_sizes, int n_in,
                              void* d_out, int out_size, void* d_ws, size_t ws_size,
                              hipStream_t stream)
{
  (void)in_sizes; (void)n_in; (void)out_size; (void)ws_size;
  const float* pf    = (const float*)d_in[0];
  const float* imf   = (const float*)d_in[1];
  const int*   gridp = (const int*)d_in[2];
  const float* Wk   =(const float*)d_in[3],  *bk   =(const float*)d_in[4];
  const float* gk   =(const float*)d_in[5],  *betak=(const float*)d_in[6];
  const float* Wfc  =(const float*)d_in[7],  *bfc  =(const float*)d_in[8];
  const float* gfc  =(const float*)d_in[9],  *betafc=(const float*)d_in[10];
  const float* Wt   =(const float*)d_in[11], *bt   =(const float*)d_in[12];
  const float* gt   =(const float*)d_in[13], *betat=(const float*)d_in[14];
  const float* Woff =(const float*)d_in[15], *boff =(const float*)d_in[16];
  const float* Wattn=(const float*)d_in[17], *battn=(const float*)d_in[18];
  const float* Wval =(const float*)d_in[19], *bval =(const float*)d_in[20];
  const float* Wout =(const float*)d_in[21], *bout =(const float*)d_in[22];
  const float* Wf   =(const float*)d_in[23], *bf   =(const float*)d_in[24];
  const float* gf   =(const float*)d_in[25], *betaf=(const float*)d_in[26];
  float* ws  = (float*)d_ws;
  float* out = (float*)d_out;

  hipLaunchKernelGGL(k0, dim3(240),  dim3(256), 0, stream, gridp, ws);
  hipLaunchKernelGGL(k1, dim3(1920), dim3(256), 0, stream, pf, imf, gridp, Wk, bk, Wfc, bfc, Wval, bval, ws);
  hipLaunchKernelGGL(k2, dim3(1152), dim3(256), 0, stream, gridp, Wt, bt, gk, betak, gfc, betafc, Woff, boff, Wattn, battn, ws);
  hipLaunchKernelGGL(k3, dim3(256),  dim3(256), 0, stream, gridp, Wout, bout, Wf, bf, gt, betat, ws);
  hipLaunchKernelGGL(k4, dim3(256),  dim3(256), 0, stream, gf, betaf, ws, out);
}